// Round 1
// 405.702 us; speedup vs baseline: 1.0170x; 1.0170x over previous
//
#include <hip/hip_runtime.h>
#include <math.h>
#include <limits.h>

#define BB 16
#define SS 4096
#define HH 1024
#define PAD_ID 0

// Fused kernel: one block per batch.
//  - Load ALL of mask/chosen/rejected for this batch up front (12 x dwordx4
//    per thread, independent -> single HBM round trip, no serial passes).
//  - start   = first i with mask!=0 (else 0)
//  - c_ind   = first i>=start with chosen==PAD (else S)
//  - r_div   = first i>=start with rejected==PAD (else S)
//  - has_div = any(chosen != rejected)
//  - r_ind   = has_div ? r_div : c_ind
//  - last    = min(c_ind, r_ind) - 1  (wrap -1 -> S-1, JAX negative-index)
//  Then gather the single hidden row of each tensor, dot with w, write the
//  two scores, and stash softplus(r-c) in ws[b] for the epilogue.
__global__ __launch_bounds__(256) void fused_kernel(
    const int*   __restrict__ chosen_ids,
    const int*   __restrict__ chosen_mask,
    const int*   __restrict__ rejected_ids,
    const float* __restrict__ chosen_hidden,
    const float* __restrict__ rejected_hidden,
    const float* __restrict__ w,
    float* __restrict__ out,
    float* __restrict__ sp_ws)
{
    const int b = blockIdx.x;
    const int t = threadIdx.x;

    const int4* msk4 = (const int4*)(chosen_mask  + (size_t)b * SS);
    const int4* cid4 = (const int4*)(chosen_ids   + (size_t)b * SS);
    const int4* rid4 = (const int4*)(rejected_ids + (size_t)b * SS);

    // Prefetch w early: independent of `last`, overlaps the scan latency.
    const float4 w4 = ((const float4*)w)[t];

    // ---- single-trip load of the whole scan working set (48 VGPRs) ----
    int4 m[4], c[4], r[4];
#pragma unroll
    for (int k = 0; k < 4; ++k) {
        m[k] = msk4[k * 256 + t];
        c[k] = cid4[k * 256 + t];
        r[k] = rid4[k * 256 + t];
    }

    // ---- start = first nonzero of mask ----
    int mstart = INT_MAX;
#pragma unroll
    for (int k = 0; k < 4; ++k) {
        const int base = k * 1024 + t * 4;
        const int v0 = m[k].x, v1 = m[k].y, v2 = m[k].z, v3 = m[k].w;
        if (v0) mstart = min(mstart, base + 0);
        if (v1) mstart = min(mstart, base + 1);
        if (v2) mstart = min(mstart, base + 2);
        if (v3) mstart = min(mstart, base + 3);
    }
    // 64-lane butterfly min, then combine 4 waves through LDS (1 barrier).
    __shared__ int sM[4];
#pragma unroll
    for (int ofs = 32; ofs > 0; ofs >>= 1)
        mstart = min(mstart, __shfl_xor(mstart, ofs, 64));
    if ((t & 63) == 0) sM[t >> 6] = mstart;
    __syncthreads();
    int start = min(min(sM[0], sM[1]), min(sM[2], sM[3]));
    if (start == INT_MAX) start = 0;

    // ---- first-pad indices + any-divergence, from cached registers ----
    int cmin = INT_MAX, rmin = INT_MAX, diff = 0;
#pragma unroll
    for (int k = 0; k < 4; ++k) {
        const int base = k * 1024 + t * 4;
        const int cv[4] = { c[k].x, c[k].y, c[k].z, c[k].w };
        const int rv[4] = { r[k].x, r[k].y, r[k].z, r[k].w };
#pragma unroll
        for (int j = 0; j < 4; ++j) {
            const int i = base + j;
            diff |= (cv[j] != rv[j]);
            if (i >= start) {
                if (cv[j] == PAD_ID) cmin = min(cmin, i);
                if (rv[j] == PAD_ID) rmin = min(rmin, i);
            }
        }
    }
    __shared__ int sA[4], sB[4], sC[4];
#pragma unroll
    for (int ofs = 32; ofs > 0; ofs >>= 1) {
        cmin = min(cmin, __shfl_xor(cmin, ofs, 64));
        rmin = min(rmin, __shfl_xor(rmin, ofs, 64));
        diff |= __shfl_xor(diff, ofs, 64);
    }
    if ((t & 63) == 0) { const int wv = t >> 6; sA[wv] = cmin; sB[wv] = rmin; sC[wv] = diff; }
    __syncthreads();
    cmin = min(min(sA[0], sA[1]), min(sA[2], sA[3]));
    rmin = min(min(sB[0], sB[1]), min(sB[2], sB[3]));
    diff = sC[0] | sC[1] | sC[2] | sC[3];

    const int c_ind = (cmin == INT_MAX) ? SS : cmin;
    const int r_div = (rmin == INT_MAX) ? SS : rmin;
    const int r_ind = diff ? r_div : c_ind;
    int last = min(c_ind, r_ind) - 1;
    if (last < 0) last += SS;            // JAX/np negative-index wrap

    // ---- gather the two needed rows, dot with w (256 x float4 == HH) ----
    const float4* ch = (const float4*)(chosen_hidden   + ((size_t)b * SS + last) * HH);
    const float4* rh = (const float4*)(rejected_hidden + ((size_t)b * SS + last) * HH);
    const float4 c4 = ch[t];
    const float4 r4 = rh[t];
    float cs = c4.x * w4.x + c4.y * w4.y + c4.z * w4.z + c4.w * w4.w;
    float rs = r4.x * w4.x + r4.y * w4.y + r4.z * w4.z + r4.w * w4.w;

    __shared__ float sF[4], sG[4];
#pragma unroll
    for (int ofs = 32; ofs > 0; ofs >>= 1) {
        cs += __shfl_xor(cs, ofs, 64);
        rs += __shfl_xor(rs, ofs, 64);
    }
    if ((t & 63) == 0) { const int wv = t >> 6; sF[wv] = cs; sG[wv] = rs; }
    __syncthreads();
    if (t == 0) {
        const float cscore = sF[0] + sF[1] + sF[2] + sF[3];
        const float rscore = sG[0] + sG[1] + sG[2] + sG[3];
        out[1 + b]      = cscore;   // chosen_mean_scores
        out[1 + BB + b] = rscore;   // rejected_mean_scores
        // -log_sigmoid(c - r) = softplus(r - c), numerically stable
        const float x  = rscore - cscore;
        sp_ws[b] = fmaxf(x, 0.0f) + log1pf(expf(-fabsf(x)));
    }
}

// Epilogue: deterministic mean of the 16 softplus values -> out[0].
__global__ __launch_bounds__(64) void loss_kernel(
    const float* __restrict__ sp_ws,
    float* __restrict__ out)
{
    const int t = threadIdx.x;
    float v = (t < BB) ? sp_ws[t] : 0.0f;
#pragma unroll
    for (int ofs = 32; ofs > 0; ofs >>= 1)
        v += __shfl_xor(v, ofs, 64);
    if (t == 0) out[0] = v * (1.0f / BB);
}

extern "C" void kernel_launch(void* const* d_in, const int* in_sizes, int n_in,
                              void* d_out, int out_size, void* d_ws, size_t ws_size,
                              hipStream_t stream) {
    const int*   chosen_ids      = (const int*)d_in[0];
    const int*   chosen_mask     = (const int*)d_in[1];
    const int*   rejected_ids    = (const int*)d_in[2];
    const float* chosen_hidden   = (const float*)d_in[3];
    const float* rejected_hidden = (const float*)d_in[4];
    const float* v_head_w        = (const float*)d_in[5];
    float* out   = (float*)d_out;
    float* sp_ws = (float*)d_ws;

    fused_kernel<<<BB, 256, 0, stream>>>(chosen_ids, chosen_mask, rejected_ids,
                                         chosen_hidden, rejected_hidden, v_head_w,
                                         out, sp_ws);
    loss_kernel<<<1, 64, 0, stream>>>(sp_ws, out);
}